// Round 4
// baseline (1631.393 us; speedup 1.0000x reference)
//
#include <hip/hip_runtime.h>
#include <math.h>

#define NPTS 4096
#define CC 0.7213475204444817f   // log2(e)/2 : exp(-s^2/2) = 2^(-CC*s^2)

__device__ __forceinline__ void gload_lds16(const float* g, float* l) {
  __builtin_amdgcn_global_load_lds(
      (const __attribute__((address_space(1))) void*)g,
      (__attribute__((address_space(3))) void*)l, 16, 0, 0);
}

// ---------------- feature MLP: coords[B,N,3] -> outT[b][h][n] (transposed) ----------------
__global__ __launch_bounds__(256) void feat_kernel(
    const float* __restrict__ coords, const float* __restrict__ W1,
    const float* __restrict__ b1, const float* __restrict__ W2,
    const float* __restrict__ b2, float* __restrict__ outT, int npts)
{
  __shared__ float sW1[3 * 64], sb1[64], sW2[64 * 64], sb2[64];
  const int tid = threadIdx.x;
  for (int i = tid; i < 192; i += 256) sW1[i] = W1[i];
  if (tid < 64) { sb1[tid] = b1[tid]; sb2[tid] = b2[tid]; }
  for (int i = tid; i < 4096; i += 256) sW2[i] = W2[i];
  __syncthreads();

  const int p  = blockIdx.x * 64 + (tid & 63);   // point index (consecutive threads -> consecutive n)
  const int qh = (tid >> 6) * 16;                // h-quarter handled by this thread
  if (p >= npts) return;
  const float c0 = coords[p * 3 + 0], c1 = coords[p * 3 + 1], c2 = coords[p * 3 + 2];

  float hid[64];
  #pragma unroll
  for (int j = 0; j < 64; ++j)
    hid[j] = fmaxf(0.f, fmaf(c0, sW1[j], fmaf(c1, sW1[64 + j], fmaf(c2, sW1[128 + j], sb1[j]))));

  float acc[16];
  #pragma unroll
  for (int h = 0; h < 16; ++h) acc[h] = sb2[qh + h];
  for (int j = 0; j < 64; ++j) {
    const float hj = hid[j];
    const float4* wrow = (const float4*)&sW2[j * 64 + qh];
    #pragma unroll
    for (int hq = 0; hq < 4; ++hq) {
      float4 wv = wrow[hq];
      acc[hq * 4 + 0] = fmaf(hj, wv.x, acc[hq * 4 + 0]);
      acc[hq * 4 + 1] = fmaf(hj, wv.y, acc[hq * 4 + 1]);
      acc[hq * 4 + 2] = fmaf(hj, wv.z, acc[hq * 4 + 2]);
      acc[hq * 4 + 3] = fmaf(hj, wv.w, acc[hq * 4 + 3]);
    }
  }
  const int b = p / NPTS, n = p % NPTS;
  #pragma unroll
  for (int h = 0; h < 16; ++h)
    outT[(size_t)(b * 64 + qh + h) * NPTS + n] = acc[h];
}

// ---------------- Vo kernel: Vo[b,n] = MLP_v(values)[b,n,:] . Wo ----------------
__global__ __launch_bounds__(256) void vo_kernel(
    const float* __restrict__ values, const float* __restrict__ Wv1,
    const float* __restrict__ bv1, const float* __restrict__ Wv2,
    const float* __restrict__ bv2, const float* __restrict__ Wo,
    float* __restrict__ VoOut, int npts)
{
  __shared__ float sWvO[64], sW1[64], sb1[64], sc0;
  const int tid = threadIdx.x;
  if (tid < 64) {
    float a = 0.f;
    for (int h = 0; h < 64; ++h) a = fmaf(Wv2[tid * 64 + h], Wo[h], a);
    sWvO[tid] = a;
    sW1[tid] = Wv1[tid];
    sb1[tid] = bv1[tid];
  } else if (tid == 64) {
    float a = 0.f;
    for (int h = 0; h < 64; ++h) a = fmaf(bv2[h], Wo[h], a);
    sc0 = a;
  }
  __syncthreads();
  const int p = blockIdx.x * 256 + tid;
  if (p >= npts) return;
  const float v = values[p];
  float a = sc0;
  #pragma unroll 8
  for (int j = 0; j < 64; ++j)
    a = fmaf(fmaxf(0.f, fmaf(v, sW1[j], sb1[j])), sWvO[j], a);
  VoOut[p] = a;
}

// ---------------- main attention kernel ----------------
// grid: B*64 blocks (one 64-m tile each), 512 threads (8 waves).
// Round-3 lesson: with 64 KiB LDS the backend computes 2 wg/CU -> 4 waves/EU
// -> 128-VGPR budget -> acc[64] spilled to scratch (5.5 GB HBM traffic); the
// waves_per_eu attribute did NOT override it. Fix via the LDS path the
// backend can't ignore: 96 KiB LDS (> 80 KiB) -> 1 wg/CU -> 2 waves/EU ->
// 256-VGPR budget. The extra 32 KiB deepens the K prefetch to 4 buffers
// (steady-state vmcnt(6): 3 chunks in flight).
__global__ __attribute__((amdgpu_flat_work_group_size(512, 512),
                          amdgpu_waves_per_eu(2, 2)))
void attn_kernel(
    const float* __restrict__ Kt, const float* __restrict__ Qt,
    const float* __restrict__ Vo, const float* __restrict__ bo,
    float* __restrict__ out)
{
  __shared__ float Qs[64 * 64];      // [h][m_local]  16 KB (reused for stats at the end)
  __shared__ float Vos[NPTS];        // Vo for this b 16 KB
  __shared__ float Ks[8][4][512];    // [wave][buf][h_local*64 + n_local] 64 KB

  const int b    = blockIdx.x >> 6;
  const int m0   = (blockIdx.x & 63) << 6;
  const int tid  = threadIdx.x;
  const int w    = tid >> 6;
  const int lane = tid & 63;
  const int lm = lane >> 3, ln = lane & 7;

  const float* __restrict__ KtB = Kt + (size_t)b * 64 * NPTS;
  const float* __restrict__ QtB = Qt + (size_t)b * 64 * NPTS;
  const float* __restrict__ VoB = Vo + (size_t)b * NPTS;

  { // stage Q tile and full Vo row into LDS (coalesced float4)
    const int h = tid >> 3, c8 = (tid & 7) * 8;
    *(float4*)&Qs[h * 64 + c8]     = *(const float4*)&QtB[(size_t)h * NPTS + m0 + c8];
    *(float4*)&Qs[h * 64 + c8 + 4] = *(const float4*)&QtB[(size_t)h * NPTS + m0 + c8 + 4];
    *(float4*)&Vos[tid * 8]     = *(const float4*)&VoB[tid * 8];
    *(float4*)&Vos[tid * 8 + 4] = *(const float4*)&VoB[tid * 8 + 4];
  }
  __syncthreads();   // drains vmcnt too -> clean counting below

  float acc[64];
  float Mt[8], num[8], den[8];
  #pragma unroll
  for (int x = 0; x < 64; ++x) acc[x] = 0.f;
  #pragma unroll
  for (int j = 0; j < 8; ++j) { Mt[j] = __builtin_inff(); num[j] = 0.f; den[j] = 0.f; }

  const int noff = w * 64 + (lane & 15) * 4;  // per-lane n column for staging
  const int hrow = lane >> 4;                 // 0..3: row within a 4-row staging instr

  // chunk c: h = (c&7)*8 + {0..7}, n base = (c>>3)*512 + w*64 ; 2 glds instrs of 1KB
  #define ISSUE_K(c_) do { \
    const int I_ = (c_) >> 3, cc_ = (c_) & 7; \
    const float* s_ = KtB + (size_t)(cc_ * 8 + hrow) * NPTS + I_ * 512 + noff; \
    float* d_ = &Ks[w][(c_) & 3][0]; \
    gload_lds16(s_, d_); \
    gload_lds16(s_ + 4 * NPTS, d_ + 256); \
  } while (0)

  ISSUE_K(0);
  ISSUE_K(1);
  ISSUE_K(2);
  ISSUE_K(3);

  for (int I = 0; I < 8; ++I) {          // n-iterations (512 n each)
    #pragma unroll
    for (int cc = 0; cc < 8; ++cc) {     // h-chunks (8 rows each)
      const int c = I * 8 + cc;
      // wait for chunk c's 2 staging instrs: outstanding = 2*min(3, 63-c)
      if (I < 7 || cc < 5) asm volatile("s_waitcnt vmcnt(6)" ::: "memory");
      else if (cc == 5)    asm volatile("s_waitcnt vmcnt(4)" ::: "memory");
      else if (cc == 6)    asm volatile("s_waitcnt vmcnt(2)" ::: "memory");
      else                 asm volatile("s_waitcnt vmcnt(0)" ::: "memory");
      __builtin_amdgcn_sched_barrier(0);
      const float* __restrict__ Kw = &Ks[w][cc & 3][ln * 8];
      const float* __restrict__ Qh = &Qs[(cc * 8) * 64 + lm * 8];
      #pragma unroll
      for (int hh = 0; hh < 8; ++hh) {
        float q[8], k[8];
        *(float4*)&q[0] = *(const float4*)(Qh + hh * 64);
        *(float4*)&q[4] = *(const float4*)(Qh + hh * 64 + 4);
        *(float4*)&k[0] = *(const float4*)(Kw + hh * 64);
        *(float4*)&k[4] = *(const float4*)(Kw + hh * 64 + 4);
        #pragma unroll
        for (int j = 0; j < 8; ++j) {
          #pragma unroll
          for (int i = 0; i < 8; ++i)
            acc[j * 8 + i] += fabsf(k[i] - q[j]);   // v_sub + v_add |src|
        }
      }
      if (c + 4 < 64) ISSUE_K(c + 4);
    }

    { // epilogue for iteration I: online softmax update (min of t = s^2)
      float vo[8];
      const int vb = I * 512 + w * 64 + ln * 8;
      *(float4*)&vo[0] = *(const float4*)&Vos[vb];
      *(float4*)&vo[4] = *(const float4*)&Vos[vb + 4];
      #pragma unroll
      for (int j = 0; j < 8; ++j) {
        float t[8];
        #pragma unroll
        for (int i = 0; i < 8; ++i) t[i] = acc[j * 8 + i] * acc[j * 8 + i];
        float rmin = fminf(fminf(fminf(t[0], t[1]), fminf(t[2], t[3])),
                           fminf(fminf(t[4], t[5]), fminf(t[6], t[7])));
        rmin = fminf(rmin, __shfl_xor(rmin, 1));
        rmin = fminf(rmin, __shfl_xor(rmin, 2));
        rmin = fminf(rmin, __shfl_xor(rmin, 4));
        const float nM = fminf(Mt[j], rmin);
        const float sc = __builtin_amdgcn_exp2f(CC * (nM - Mt[j])); // inf start -> 0
        num[j] *= sc; den[j] *= sc; Mt[j] = nM;
        const float base = CC * nM;
        #pragma unroll
        for (int i = 0; i < 8; ++i) {
          const float wgt = __builtin_amdgcn_exp2f(fmaf(-CC, t[i], base));
          den[j] += wgt;
          num[j] = fmaf(wgt, vo[i], num[j]);
          acc[j * 8 + i] = 0.f;
        }
      }
    }
  }

  // reduce num/den over the 8 ln-lanes sharing each m (Mt already uniform)
  #pragma unroll
  for (int j = 0; j < 8; ++j) {
    #pragma unroll
    for (int off = 1; off < 8; off <<= 1) {
      num[j] += __shfl_xor(num[j], off);
      den[j] += __shfl_xor(den[j], off);
    }
  }
  __syncthreads();                 // everyone done reading Qs/Ks
  if (ln == 0) {
    #pragma unroll
    for (int j = 0; j < 8; ++j) {
      const int ml = lm * 8 + j;
      Qs[(w * 64 + ml) * 3 + 0] = Mt[j];
      Qs[(w * 64 + ml) * 3 + 1] = num[j];
      Qs[(w * 64 + ml) * 3 + 2] = den[j];
    }
  }
  __syncthreads();
  if (tid < 64) {                  // merge the 8 waves' partial softmax states
    float M = __builtin_inff();
    #pragma unroll
    for (int ww = 0; ww < 8; ++ww) M = fminf(M, Qs[(ww * 64 + tid) * 3]);
    float Ns = 0.f, Ds = 0.f;
    #pragma unroll
    for (int ww = 0; ww < 8; ++ww) {
      const float f = __builtin_amdgcn_exp2f(CC * (M - Qs[(ww * 64 + tid) * 3]));
      Ns = fmaf(Qs[(ww * 64 + tid) * 3 + 1], f, Ns);
      Ds = fmaf(Qs[(ww * 64 + tid) * 3 + 2], f, Ds);
    }
    out[(size_t)b * NPTS + m0 + tid] = Ns / Ds + bo[0];
  }
}

extern "C" void kernel_launch(void* const* d_in, const int* in_sizes, int n_in,
                              void* d_out, int out_size, void* d_ws, size_t ws_size,
                              hipStream_t stream)
{
  const float* coords_f = (const float*)d_in[0];
  const float* values_f = (const float*)d_in[1];
  const float* coords_t = (const float*)d_in[2];
  const float* Wk1 = (const float*)d_in[3];
  const float* bk1 = (const float*)d_in[4];
  const float* Wk2 = (const float*)d_in[5];
  const float* bk2 = (const float*)d_in[6];
  const float* Wq1 = (const float*)d_in[7];
  const float* bq1 = (const float*)d_in[8];
  const float* Wq2 = (const float*)d_in[9];
  const float* bq2 = (const float*)d_in[10];
  const float* Wv1 = (const float*)d_in[11];
  const float* bv1 = (const float*)d_in[12];
  const float* Wv2 = (const float*)d_in[13];
  const float* bv2 = (const float*)d_in[14];
  const float* Wo  = (const float*)d_in[15];
  const float* bo  = (const float*)d_in[16];

  const int B    = in_sizes[0] / (NPTS * 3);
  const int npts = B * NPTS;

  float* Kt  = (float*)d_ws;                       // [B][64][N]
  float* Qt  = Kt + (size_t)B * 64 * NPTS;         // [B][64][M]
  float* VoW = Qt + (size_t)B * 64 * NPTS;         // [B][N]

  feat_kernel<<<npts / 64, 256, 0, stream>>>(coords_f, Wk1, bk1, Wk2, bk2, Kt, npts);
  feat_kernel<<<npts / 64, 256, 0, stream>>>(coords_t, Wq1, bq1, Wq2, bq2, Qt, npts);
  vo_kernel<<<npts / 256, 256, 0, stream>>>(values_f, Wv1, bv1, Wv2, bv2, Wo, VoW, npts);
  attn_kernel<<<B * 64, 512, 0, stream>>>(Kt, Qt, VoW, bo, (float*)d_out);
}

// Round 5
// 1574.422 us; speedup vs baseline: 1.0362x; 1.0362x over previous
//
#include <hip/hip_runtime.h>
#include <math.h>

#define NPTS 4096
#define CC 0.7213475204444817f   // log2(e)/2 : exp(-s^2/2) = 2^(-CC*s^2)

__device__ __forceinline__ void gload_lds16(const float* g, float* l) {
  __builtin_amdgcn_global_load_lds(
      (const __attribute__((address_space(1))) void*)g,
      (__attribute__((address_space(3))) void*)l, 16, 0, 0);
}

// ---------------- feature MLP: coords[B,N,3] -> outT[b][h][n] (transposed) ----------------
__global__ __launch_bounds__(256) void feat_kernel(
    const float* __restrict__ coords, const float* __restrict__ W1,
    const float* __restrict__ b1, const float* __restrict__ W2,
    const float* __restrict__ b2, float* __restrict__ outT, int npts)
{
  __shared__ float sW1[3 * 64], sb1[64], sW2[64 * 64], sb2[64];
  const int tid = threadIdx.x;
  for (int i = tid; i < 192; i += 256) sW1[i] = W1[i];
  if (tid < 64) { sb1[tid] = b1[tid]; sb2[tid] = b2[tid]; }
  for (int i = tid; i < 4096; i += 256) sW2[i] = W2[i];
  __syncthreads();

  const int p  = blockIdx.x * 64 + (tid & 63);   // point index (consecutive threads -> consecutive n)
  const int qh = (tid >> 6) * 16;                // h-quarter handled by this thread
  if (p >= npts) return;
  const float c0 = coords[p * 3 + 0], c1 = coords[p * 3 + 1], c2 = coords[p * 3 + 2];

  float hid[64];
  #pragma unroll
  for (int j = 0; j < 64; ++j)
    hid[j] = fmaxf(0.f, fmaf(c0, sW1[j], fmaf(c1, sW1[64 + j], fmaf(c2, sW1[128 + j], sb1[j]))));

  float acc[16];
  #pragma unroll
  for (int h = 0; h < 16; ++h) acc[h] = sb2[qh + h];
  for (int j = 0; j < 64; ++j) {
    const float hj = hid[j];
    const float4* wrow = (const float4*)&sW2[j * 64 + qh];
    #pragma unroll
    for (int hq = 0; hq < 4; ++hq) {
      float4 wv = wrow[hq];
      acc[hq * 4 + 0] = fmaf(hj, wv.x, acc[hq * 4 + 0]);
      acc[hq * 4 + 1] = fmaf(hj, wv.y, acc[hq * 4 + 1]);
      acc[hq * 4 + 2] = fmaf(hj, wv.z, acc[hq * 4 + 2]);
      acc[hq * 4 + 3] = fmaf(hj, wv.w, acc[hq * 4 + 3]);
    }
  }
  const int b = p / NPTS, n = p % NPTS;
  #pragma unroll
  for (int h = 0; h < 16; ++h)
    outT[(size_t)(b * 64 + qh + h) * NPTS + n] = acc[h];
}

// ---------------- Vo kernel: Vo[b,n] = MLP_v(values)[b,n,:] . Wo ----------------
__global__ __launch_bounds__(256) void vo_kernel(
    const float* __restrict__ values, const float* __restrict__ Wv1,
    const float* __restrict__ bv1, const float* __restrict__ Wv2,
    const float* __restrict__ bv2, const float* __restrict__ Wo,
    float* __restrict__ VoOut, int npts)
{
  __shared__ float sWvO[64], sW1[64], sb1[64], sc0;
  const int tid = threadIdx.x;
  if (tid < 64) {
    float a = 0.f;
    for (int h = 0; h < 64; ++h) a = fmaf(Wv2[tid * 64 + h], Wo[h], a);
    sWvO[tid] = a;
    sW1[tid] = Wv1[tid];
    sb1[tid] = bv1[tid];
  } else if (tid == 64) {
    float a = 0.f;
    for (int h = 0; h < 64; ++h) a = fmaf(bv2[h], Wo[h], a);
    sc0 = a;
  }
  __syncthreads();
  const int p = blockIdx.x * 256 + tid;
  if (p >= npts) return;
  const float v = values[p];
  float a = sc0;
  #pragma unroll 8
  for (int j = 0; j < 64; ++j)
    a = fmaf(fmaxf(0.f, fmaf(v, sW1[j], sb1[j])), sWvO[j], a);
  VoOut[p] = a;
}

// ---------------- main attention kernel ----------------
// grid: B*64 blocks (one 64-m tile each), 512 threads (8 waves).
// Rounds 1-4 lesson: the allocator pins VGPR=128 no matter what attributes we
// pass, and the old structure needed ~140 regs -> inner-loop spill -> 5.5 GB
// scratch HBM traffic (the whole 1.6 ms). Fix structurally: move num/den
// softmax state to per-thread LDS slots (touched 8x per kernel), drop t[]
// (min(s^2) = (min s)^2 since s>=0). Peak pressure ~106 < 128 -> no spill.
__global__ void __launch_bounds__(512)
attn_kernel(
    const float* __restrict__ Kt, const float* __restrict__ Qt,
    const float* __restrict__ Vo, const float* __restrict__ bo,
    float* __restrict__ out)
{
  __shared__ float Qs[64 * 64];      // [h][m_local]  16 KB
  __shared__ float Vos[NPTS];        // Vo for this b  16 KB
  __shared__ float Ks[8][2][512];    // [wave][buf][h_local*64 + n_local] 32 KB
  __shared__ float MtL[512];         // [w][m_local]  final-merge staging  2 KB
  __shared__ float numL[4096];       // [w][m_local][ln] running numerator 16 KB
  __shared__ float denL[4096];       // [w][m_local][ln] running denominator 16 KB

  const int b    = blockIdx.x >> 6;
  const int m0   = (blockIdx.x & 63) << 6;
  const int tid  = threadIdx.x;
  const int w    = tid >> 6;
  const int lane = tid & 63;
  const int lm = lane >> 3, ln = lane & 7;

  const float* __restrict__ KtB = Kt + (size_t)b * 64 * NPTS;
  const float* __restrict__ QtB = Qt + (size_t)b * 64 * NPTS;
  const float* __restrict__ VoB = Vo + (size_t)b * NPTS;

  { // stage Q tile and full Vo row into LDS (coalesced float4); zero own stats
    const int h = tid >> 3, c8 = (tid & 7) * 8;
    *(float4*)&Qs[h * 64 + c8]     = *(const float4*)&QtB[(size_t)h * NPTS + m0 + c8];
    *(float4*)&Qs[h * 64 + c8 + 4] = *(const float4*)&QtB[(size_t)h * NPTS + m0 + c8 + 4];
    *(float4*)&Vos[tid * 8]     = *(const float4*)&VoB[tid * 8];
    *(float4*)&Vos[tid * 8 + 4] = *(const float4*)&VoB[tid * 8 + 4];
    #pragma unroll
    for (int j = 0; j < 8; ++j) {
      numL[w * 512 + lm * 64 + j * 8 + ln] = 0.f;
      denL[w * 512 + lm * 64 + j * 8 + ln] = 0.f;
    }
  }
  __syncthreads();   // drains vmcnt too -> clean counting below

  float acc[64];
  float Mt[8];
  #pragma unroll
  for (int x = 0; x < 64; ++x) acc[x] = 0.f;
  #pragma unroll
  for (int j = 0; j < 8; ++j) Mt[j] = __builtin_inff();

  const int noff = w * 64 + (lane & 15) * 4;  // per-lane n column for staging
  const int hrow = lane >> 4;                 // 0..3: row within a 4-row staging instr

  // chunk c: h = (c&7)*8 + {0..7}, n base = (c>>3)*512 + w*64 ; 2 glds instrs of 1KB
  #define ISSUE_K(c_) do { \
    const int I_ = (c_) >> 3, cc_ = (c_) & 7; \
    const float* s_ = KtB + (size_t)(cc_ * 8 + hrow) * NPTS + I_ * 512 + noff; \
    float* d_ = &Ks[w][(c_) & 1][0]; \
    gload_lds16(s_, d_); \
    gload_lds16(s_ + 4 * NPTS, d_ + 256); \
  } while (0)

  ISSUE_K(0);
  ISSUE_K(1);

  for (int I = 0; I < 8; ++I) {          // n-iterations (512 n each)
    #pragma unroll
    for (int cc = 0; cc < 8; ++cc) {     // h-chunks (8 rows each)
      const int c = I * 8 + cc;
      if (c < 63) asm volatile("s_waitcnt vmcnt(2)" ::: "memory");
      else        asm volatile("s_waitcnt vmcnt(0)" ::: "memory");
      __builtin_amdgcn_sched_barrier(0);
      const float* __restrict__ Kw = &Ks[w][cc & 1][ln * 8];
      const float* __restrict__ Qh = &Qs[(cc * 8) * 64 + lm * 8];
      #pragma unroll
      for (int hh = 0; hh < 8; ++hh) {
        float q[8], k[8];
        *(float4*)&q[0] = *(const float4*)(Qh + hh * 64);
        *(float4*)&q[4] = *(const float4*)(Qh + hh * 64 + 4);
        *(float4*)&k[0] = *(const float4*)(Kw + hh * 64);
        *(float4*)&k[4] = *(const float4*)(Kw + hh * 64 + 4);
        #pragma unroll
        for (int j = 0; j < 8; ++j) {
          #pragma unroll
          for (int i = 0; i < 8; ++i)
            acc[j * 8 + i] += fabsf(k[i] - q[j]);   // v_sub + v_add |src|
        }
      }
      if (c + 2 < 64) ISSUE_K(c + 2);
    }

    { // epilogue for iteration I: online softmax update (min s -> min s^2)
      float vo[8];
      const int vb = I * 512 + w * 64 + ln * 8;
      *(float4*)&vo[0] = *(const float4*)&Vos[vb];
      *(float4*)&vo[4] = *(const float4*)&Vos[vb + 4];
      #pragma unroll
      for (int j = 0; j < 8; ++j) {
        // acc >= 0, so min(s^2) == (min s)^2 — no t[] array needed
        float rmin = fminf(fminf(fminf(acc[j*8+0], acc[j*8+1]), fminf(acc[j*8+2], acc[j*8+3])),
                           fminf(fminf(acc[j*8+4], acc[j*8+5]), fminf(acc[j*8+6], acc[j*8+7])));
        rmin = fminf(rmin, __shfl_xor(rmin, 1));
        rmin = fminf(rmin, __shfl_xor(rmin, 2));
        rmin = fminf(rmin, __shfl_xor(rmin, 4));
        const float nM = fminf(Mt[j], rmin * rmin);
        const float sc = __builtin_amdgcn_exp2f(CC * (nM - Mt[j])); // inf start -> 0
        const int slot = w * 512 + lm * 64 + j * 8 + ln;
        float nm = numL[slot] * sc;
        float dn = denL[slot] * sc;
        Mt[j] = nM;
        const float base = CC * nM;
        #pragma unroll
        for (int i = 0; i < 8; ++i) {
          const float a = acc[j * 8 + i];
          const float wgt = __builtin_amdgcn_exp2f(fmaf(-CC, a * a, base));
          dn += wgt;
          nm = fmaf(wgt, vo[i], nm);
          acc[j * 8 + i] = 0.f;
        }
        numL[slot] = nm;
        denL[slot] = dn;
      }
    }
  }

  // publish per-wave Mt (uniform across the 8 ln-lanes of each m)
  if (ln == 0) {
    #pragma unroll
    for (int j = 0; j < 8; ++j)
      MtL[w * 64 + lm * 8 + j] = Mt[j];
  }
  __syncthreads();

  if (tid < 64) {                  // merge the 8 waves' partial softmax states
    const int m = tid;
    float M = __builtin_inff();
    #pragma unroll
    for (int ww = 0; ww < 8; ++ww) M = fminf(M, MtL[ww * 64 + m]);
    float Ns = 0.f, Ds = 0.f;
    #pragma unroll
    for (int ww = 0; ww < 8; ++ww) {
      const float f = __builtin_amdgcn_exp2f(CC * (M - MtL[ww * 64 + m]));
      float ns = 0.f, ds = 0.f;
      #pragma unroll
      for (int l = 0; l < 8; ++l) {
        ns += numL[ww * 512 + m * 8 + l];
        ds += denL[ww * 512 + m * 8 + l];
      }
      Ns = fmaf(ns, f, Ns);
      Ds = fmaf(ds, f, Ds);
    }
    out[(size_t)b * NPTS + m0 + m] = Ns / Ds + bo[0];
  }
}

extern "C" void kernel_launch(void* const* d_in, const int* in_sizes, int n_in,
                              void* d_out, int out_size, void* d_ws, size_t ws_size,
                              hipStream_t stream)
{
  const float* coords_f = (const float*)d_in[0];
  const float* values_f = (const float*)d_in[1];
  const float* coords_t = (const float*)d_in[2];
  const float* Wk1 = (const float*)d_in[3];
  const float* bk1 = (const float*)d_in[4];
  const float* Wk2 = (const float*)d_in[5];
  const float* bk2 = (const float*)d_in[6];
  const float* Wq1 = (const float*)d_in[7];
  const float* bq1 = (const float*)d_in[8];
  const float* Wq2 = (const float*)d_in[9];
  const float* bq2 = (const float*)d_in[10];
  const float* Wv1 = (const float*)d_in[11];
  const float* bv1 = (const float*)d_in[12];
  const float* Wv2 = (const float*)d_in[13];
  const float* bv2 = (const float*)d_in[14];
  const float* Wo  = (const float*)d_in[15];
  const float* bo  = (const float*)d_in[16];

  const int B    = in_sizes[0] / (NPTS * 3);
  const int npts = B * NPTS;

  float* Kt  = (float*)d_ws;                       // [B][64][N]
  float* Qt  = Kt + (size_t)B * 64 * NPTS;         // [B][64][M]
  float* VoW = Qt + (size_t)B * 64 * NPTS;         // [B][N]

  feat_kernel<<<npts / 64, 256, 0, stream>>>(coords_f, Wk1, bk1, Wk2, bk2, Kt, npts);
  feat_kernel<<<npts / 64, 256, 0, stream>>>(coords_t, Wq1, bq1, Wq2, bq2, Qt, npts);
  vo_kernel<<<npts / 256, 256, 0, stream>>>(values_f, Wv1, bv1, Wv2, bv2, Wo, VoW, npts);
  attn_kernel<<<B * 64, 512, 0, stream>>>(Kt, Qt, VoW, bo, (float*)d_out);
}

// Round 6
// 326.921 us; speedup vs baseline: 4.9902x; 4.8159x over previous
//
#include <hip/hip_runtime.h>
#include <math.h>

#define NPTS 4096
#define CC 0.7213475204444817f   // log2(e)/2 : exp(-s^2/2) = 2^(-CC*s^2)

__device__ __forceinline__ void gload_lds16(const float* g, float* l) {
  __builtin_amdgcn_global_load_lds(
      (const __attribute__((address_space(1))) void*)g,
      (__attribute__((address_space(3))) void*)l, 16, 0, 0);
}

// ---------------- feature MLP: coords[B,N,3] -> outT[b][h][n] (transposed) ----------------
__global__ __launch_bounds__(256) void feat_kernel(
    const float* __restrict__ coords, const float* __restrict__ W1,
    const float* __restrict__ b1, const float* __restrict__ W2,
    const float* __restrict__ b2, float* __restrict__ outT, int npts)
{
  __shared__ float sW1[3 * 64], sb1[64], sW2[64 * 64], sb2[64];
  const int tid = threadIdx.x;
  for (int i = tid; i < 192; i += 256) sW1[i] = W1[i];
  if (tid < 64) { sb1[tid] = b1[tid]; sb2[tid] = b2[tid]; }
  for (int i = tid; i < 4096; i += 256) sW2[i] = W2[i];
  __syncthreads();

  const int p  = blockIdx.x * 64 + (tid & 63);   // point index (consecutive threads -> consecutive n)
  const int qh = (tid >> 6) * 16;                // h-quarter handled by this thread
  if (p >= npts) return;
  const float c0 = coords[p * 3 + 0], c1 = coords[p * 3 + 1], c2 = coords[p * 3 + 2];

  float hid[64];
  #pragma unroll
  for (int j = 0; j < 64; ++j)
    hid[j] = fmaxf(0.f, fmaf(c0, sW1[j], fmaf(c1, sW1[64 + j], fmaf(c2, sW1[128 + j], sb1[j]))));

  float acc[16];
  #pragma unroll
  for (int h = 0; h < 16; ++h) acc[h] = sb2[qh + h];
  for (int j = 0; j < 64; ++j) {
    const float hj = hid[j];
    const float4* wrow = (const float4*)&sW2[j * 64 + qh];
    #pragma unroll
    for (int hq = 0; hq < 4; ++hq) {
      float4 wv = wrow[hq];
      acc[hq * 4 + 0] = fmaf(hj, wv.x, acc[hq * 4 + 0]);
      acc[hq * 4 + 1] = fmaf(hj, wv.y, acc[hq * 4 + 1]);
      acc[hq * 4 + 2] = fmaf(hj, wv.z, acc[hq * 4 + 2]);
      acc[hq * 4 + 3] = fmaf(hj, wv.w, acc[hq * 4 + 3]);
    }
  }
  const int b = p / NPTS, n = p % NPTS;
  #pragma unroll
  for (int h = 0; h < 16; ++h)
    outT[(size_t)(b * 64 + qh + h) * NPTS + n] = acc[h];
}

// ---------------- Vo kernel: Vo[b,n] = MLP_v(values)[b,n,:] . Wo ----------------
__global__ __launch_bounds__(256) void vo_kernel(
    const float* __restrict__ values, const float* __restrict__ Wv1,
    const float* __restrict__ bv1, const float* __restrict__ Wv2,
    const float* __restrict__ bv2, const float* __restrict__ Wo,
    float* __restrict__ VoOut, int npts)
{
  __shared__ float sWvO[64], sW1[64], sb1[64], sc0;
  const int tid = threadIdx.x;
  if (tid < 64) {
    float a = 0.f;
    for (int h = 0; h < 64; ++h) a = fmaf(Wv2[tid * 64 + h], Wo[h], a);
    sWvO[tid] = a;
    sW1[tid] = Wv1[tid];
    sb1[tid] = bv1[tid];
  } else if (tid == 64) {
    float a = 0.f;
    for (int h = 0; h < 64; ++h) a = fmaf(bv2[h], Wo[h], a);
    sc0 = a;
  }
  __syncthreads();
  const int p = blockIdx.x * 256 + tid;
  if (p >= npts) return;
  const float v = values[p];
  float a = sc0;
  #pragma unroll 8
  for (int j = 0; j < 64; ++j)
    a = fmaf(fmaxf(0.f, fmaf(v, sW1[j], sb1[j])), sWvO[j], a);
  VoOut[p] = a;
}

// ---------------- main attention kernel ----------------
// grid: B*64 blocks (one 64-m tile each), 512 threads (8 waves).
// Rounds 1-5 lesson: the allocator's 128-VGPR budget is immovable, and the
// old structure (acc[64] + fully-unrolled hh loop batching 8x16 ds_read
// operands) demanded ~200 regs -> acc spilled to scratch every chunk
// (5.3 GB HBM, the whole 1.6 ms). Design for <=128 instead:
//   - acc[32] (8m x 4n lane tile; wave = 32 n/step, 16 n-iterations)
//   - hh loop rolled (#pragma unroll 2): operand live range ~24 regs
//   - 1 KB chunks, 4-buffer pipeline, steady-state vmcnt(3)
//   - num/den softmax state in LDS, slot = j*64+lane (2-way, conflict-free)
__global__ void __launch_bounds__(512)
attn_kernel(
    const float* __restrict__ Kt, const float* __restrict__ Qt,
    const float* __restrict__ Vo, const float* __restrict__ bo,
    float* __restrict__ out)
{
  __shared__ float Qs[64 * 64];      // [h][m_local]  16 KB
  __shared__ float Vos[NPTS];        // Vo for this b  16 KB
  __shared__ float Ks[8][4][256];    // [wave][buf][h8*32 + n32] 32 KB
  __shared__ float MtL[512];         // [w][m_local]  final-merge staging 2 KB
  __shared__ float numL[4096];       // [w][j*64+lane] running numerator 16 KB
  __shared__ float denL[4096];       // [w][j*64+lane] running denominator 16 KB

  const int b    = blockIdx.x >> 6;
  const int m0   = (blockIdx.x & 63) << 6;
  const int tid  = threadIdx.x;
  const int w    = tid >> 6;
  const int lane = tid & 63;
  const int lm = lane >> 3, ln = lane & 7;

  const float* __restrict__ KtB = Kt + (size_t)b * 64 * NPTS;
  const float* __restrict__ QtB = Qt + (size_t)b * 64 * NPTS;
  const float* __restrict__ VoB = Vo + (size_t)b * NPTS;

  { // stage Q tile and full Vo row into LDS (coalesced float4); zero own stats
    const int h = tid >> 3, c8 = (tid & 7) * 8;
    *(float4*)&Qs[h * 64 + c8]     = *(const float4*)&QtB[(size_t)h * NPTS + m0 + c8];
    *(float4*)&Qs[h * 64 + c8 + 4] = *(const float4*)&QtB[(size_t)h * NPTS + m0 + c8 + 4];
    *(float4*)&Vos[tid * 8]     = *(const float4*)&VoB[tid * 8];
    *(float4*)&Vos[tid * 8 + 4] = *(const float4*)&VoB[tid * 8 + 4];
    #pragma unroll
    for (int j = 0; j < 8; ++j) {
      numL[w * 512 + j * 64 + lane] = 0.f;
      denL[w * 512 + j * 64 + lane] = 0.f;
    }
  }
  __syncthreads();   // drains vmcnt too -> clean counting below

  float acc[32];
  float Mt[8];
  #pragma unroll
  for (int x = 0; x < 32; ++x) acc[x] = 0.f;
  #pragma unroll
  for (int j = 0; j < 8; ++j) Mt[j] = __builtin_inff();

  const int hrow = lane >> 3;                 // 0..7: h row within a staging instr
  const int noff = w * 32 + (lane & 7) * 4;   // per-lane n column for staging

  // chunk c (0..127): h = (c&7)*8 + {0..7}, n base = (c>>3)*256 + w*32
  // one gload_lds16 instr = 64 lanes x 16 B = 1 KB = 8h x 32n
  #define ISSUE_K(c_) do { \
    const int I_ = (c_) >> 3, cc_ = (c_) & 7; \
    const float* s_ = KtB + (size_t)(cc_ * 8 + hrow) * NPTS + I_ * 256 + noff; \
    gload_lds16(s_, &Ks[w][(c_) & 3][0]); \
  } while (0)

  ISSUE_K(0);
  ISSUE_K(1);
  ISSUE_K(2);
  ISSUE_K(3);

  for (int I = 0; I < 16; ++I) {         // n-iterations (256 n each; wave owns 32)
    #pragma unroll
    for (int cc = 0; cc < 8; ++cc) {     // h-chunks (8 rows each)
      const int c = I * 8 + cc;
      // outstanding at this point: chunks c..min(c+3,127)
      if (I < 15 || cc < 5) asm volatile("s_waitcnt vmcnt(3)" ::: "memory");
      else if (cc == 5)     asm volatile("s_waitcnt vmcnt(2)" ::: "memory");
      else if (cc == 6)     asm volatile("s_waitcnt vmcnt(1)" ::: "memory");
      else                  asm volatile("s_waitcnt vmcnt(0)" ::: "memory");
      __builtin_amdgcn_sched_barrier(0);
      const float* __restrict__ Kw = &Ks[w][cc & 3][ln * 4];
      const float* __restrict__ Qh = &Qs[(cc * 8) * 64 + lm * 8];
      #pragma unroll 2
      for (int hh = 0; hh < 8; ++hh) {
        float q[8], k[4];
        *(float4*)&q[0] = *(const float4*)(Qh + hh * 64);
        *(float4*)&q[4] = *(const float4*)(Qh + hh * 64 + 4);
        *(float4*)&k[0] = *(const float4*)(Kw + hh * 32);
        #pragma unroll
        for (int j = 0; j < 8; ++j) {
          #pragma unroll
          for (int i = 0; i < 4; ++i)
            acc[j * 4 + i] += fabsf(k[i] - q[j]);   // v_sub + v_add |src|
        }
      }
      if (c + 4 < 128) ISSUE_K(c + 4);
    }

    { // epilogue for iteration I: online softmax update (min s -> min s^2)
      float vo[4];
      const int vb = I * 256 + w * 32 + ln * 4;
      *(float4*)&vo[0] = *(const float4*)&Vos[vb];
      #pragma unroll
      for (int j = 0; j < 8; ++j) {
        // acc >= 0, so min(s^2) == (min s)^2
        float rmin = fminf(fminf(acc[j*4+0], acc[j*4+1]), fminf(acc[j*4+2], acc[j*4+3]));
        rmin = fminf(rmin, __shfl_xor(rmin, 1));
        rmin = fminf(rmin, __shfl_xor(rmin, 2));
        rmin = fminf(rmin, __shfl_xor(rmin, 4));
        const float nM = fminf(Mt[j], rmin * rmin);
        const float sc = __builtin_amdgcn_exp2f(CC * (nM - Mt[j])); // inf start -> 0
        const int slot = w * 512 + j * 64 + lane;
        float nm = numL[slot] * sc;
        float dn = denL[slot] * sc;
        Mt[j] = nM;
        const float base = CC * nM;
        #pragma unroll
        for (int i = 0; i < 4; ++i) {
          const float a = acc[j * 4 + i];
          const float wgt = __builtin_amdgcn_exp2f(fmaf(-CC, a * a, base));
          dn += wgt;
          nm = fmaf(wgt, vo[i], nm);
          acc[j * 4 + i] = 0.f;
        }
        numL[slot] = nm;
        denL[slot] = dn;
      }
    }
  }

  // publish per-wave Mt (uniform across the 8 ln-lanes of each m)
  if (ln == 0) {
    #pragma unroll
    for (int j = 0; j < 8; ++j)
      MtL[w * 64 + lm * 8 + j] = Mt[j];
  }
  __syncthreads();

  if (tid < 64) {                  // merge the 8 waves' partial softmax states
    const int m = tid;             // m = lm*8 + j  ->  j = m&7, lm = m>>3
    float M = __builtin_inff();
    #pragma unroll
    for (int ww = 0; ww < 8; ++ww) M = fminf(M, MtL[ww * 64 + m]);
    float Ns = 0.f, Ds = 0.f;
    #pragma unroll
    for (int ww = 0; ww < 8; ++ww) {
      const float f = __builtin_amdgcn_exp2f(CC * (M - MtL[ww * 64 + m]));
      float ns = 0.f, ds = 0.f;
      #pragma unroll
      for (int l = 0; l < 8; ++l) {
        ns += numL[ww * 512 + (m & 7) * 64 + (m >> 3) * 8 + l];
        ds += denL[ww * 512 + (m & 7) * 64 + (m >> 3) * 8 + l];
      }
      Ns = fmaf(ns, f, Ns);
      Ds = fmaf(ds, f, Ds);
    }
    out[(size_t)b * NPTS + m0 + m] = Ns / Ds + bo[0];
  }
}

extern "C" void kernel_launch(void* const* d_in, const int* in_sizes, int n_in,
                              void* d_out, int out_size, void* d_ws, size_t ws_size,
                              hipStream_t stream)
{
  const float* coords_f = (const float*)d_in[0];
  const float* values_f = (const float*)d_in[1];
  const float* coords_t = (const float*)d_in[2];
  const float* Wk1 = (const float*)d_in[3];
  const float* bk1 = (const float*)d_in[4];
  const float* Wk2 = (const float*)d_in[5];
  const float* bk2 = (const float*)d_in[6];
  const float* Wq1 = (const float*)d_in[7];
  const float* bq1 = (const float*)d_in[8];
  const float* Wq2 = (const float*)d_in[9];
  const float* bq2 = (const float*)d_in[10];
  const float* Wv1 = (const float*)d_in[11];
  const float* bv1 = (const float*)d_in[12];
  const float* Wv2 = (const float*)d_in[13];
  const float* bv2 = (const float*)d_in[14];
  const float* Wo  = (const float*)d_in[15];
  const float* bo  = (const float*)d_in[16];

  const int B    = in_sizes[0] / (NPTS * 3);
  const int npts = B * NPTS;

  float* Kt  = (float*)d_ws;                       // [B][64][N]
  float* Qt  = Kt + (size_t)B * 64 * NPTS;         // [B][64][M]
  float* VoW = Qt + (size_t)B * 64 * NPTS;         // [B][N]

  feat_kernel<<<npts / 64, 256, 0, stream>>>(coords_f, Wk1, bk1, Wk2, bk2, Kt, npts);
  feat_kernel<<<npts / 64, 256, 0, stream>>>(coords_t, Wq1, bq1, Wq2, bq2, Qt, npts);
  vo_kernel<<<npts / 256, 256, 0, stream>>>(values_f, Wv1, bv1, Wv2, bv2, Wo, VoW, npts);
  attn_kernel<<<B * 64, 512, 0, stream>>>(Kt, Qt, VoW, bo, (float*)d_out);
}

// Round 7
// 314.832 us; speedup vs baseline: 5.1818x; 1.0384x over previous
//
#include <hip/hip_runtime.h>
#include <math.h>

#define NPTS 4096
#define CC 0.7213475204444817f   // log2(e)/2 : exp(-s^2/2) = 2^(-CC*s^2)

__device__ __forceinline__ void gload_lds16(const float* g, float* l) {
  __builtin_amdgcn_global_load_lds(
      (const __attribute__((address_space(1))) void*)g,
      (__attribute__((address_space(3))) void*)l, 16, 0, 0);
}

// ---------------- feature MLP: coords[B,N,3] -> outT[b][h][n] (transposed) ----------------
__global__ __launch_bounds__(256) void feat_kernel(
    const float* __restrict__ coords, const float* __restrict__ W1,
    const float* __restrict__ b1, const float* __restrict__ W2,
    const float* __restrict__ b2, float* __restrict__ outT, int npts)
{
  __shared__ float sW1[3 * 64], sb1[64], sW2[64 * 64], sb2[64];
  const int tid = threadIdx.x;
  for (int i = tid; i < 192; i += 256) sW1[i] = W1[i];
  if (tid < 64) { sb1[tid] = b1[tid]; sb2[tid] = b2[tid]; }
  for (int i = tid; i < 4096; i += 256) sW2[i] = W2[i];
  __syncthreads();

  const int p  = blockIdx.x * 64 + (tid & 63);   // point index (consecutive threads -> consecutive n)
  const int qh = (tid >> 6) * 16;                // h-quarter handled by this thread
  if (p >= npts) return;
  const float c0 = coords[p * 3 + 0], c1 = coords[p * 3 + 1], c2 = coords[p * 3 + 2];

  float hid[64];
  #pragma unroll
  for (int j = 0; j < 64; ++j)
    hid[j] = fmaxf(0.f, fmaf(c0, sW1[j], fmaf(c1, sW1[64 + j], fmaf(c2, sW1[128 + j], sb1[j]))));

  float acc[16];
  #pragma unroll
  for (int h = 0; h < 16; ++h) acc[h] = sb2[qh + h];
  for (int j = 0; j < 64; ++j) {
    const float hj = hid[j];
    const float4* wrow = (const float4*)&sW2[j * 64 + qh];
    #pragma unroll
    for (int hq = 0; hq < 4; ++hq) {
      float4 wv = wrow[hq];
      acc[hq * 4 + 0] = fmaf(hj, wv.x, acc[hq * 4 + 0]);
      acc[hq * 4 + 1] = fmaf(hj, wv.y, acc[hq * 4 + 1]);
      acc[hq * 4 + 2] = fmaf(hj, wv.z, acc[hq * 4 + 2]);
      acc[hq * 4 + 3] = fmaf(hj, wv.w, acc[hq * 4 + 3]);
    }
  }
  const int b = p / NPTS, n = p % NPTS;
  #pragma unroll
  for (int h = 0; h < 16; ++h)
    outT[(size_t)(b * 64 + qh + h) * NPTS + n] = acc[h];
}

// ---------------- Vo kernel: Vo[b,n] = MLP_v(values)[b,n,:] . Wo ----------------
__global__ __launch_bounds__(256) void vo_kernel(
    const float* __restrict__ values, const float* __restrict__ Wv1,
    const float* __restrict__ bv1, const float* __restrict__ Wv2,
    const float* __restrict__ bv2, const float* __restrict__ Wo,
    float* __restrict__ VoOut, int npts)
{
  __shared__ float sWvO[64], sW1[64], sb1[64], sc0;
  const int tid = threadIdx.x;
  if (tid < 64) {
    float a = 0.f;
    for (int h = 0; h < 64; ++h) a = fmaf(Wv2[tid * 64 + h], Wo[h], a);
    sWvO[tid] = a;
    sW1[tid] = Wv1[tid];
    sb1[tid] = bv1[tid];
  } else if (tid == 64) {
    float a = 0.f;
    for (int h = 0; h < 64; ++h) a = fmaf(bv2[h], Wo[h], a);
    sc0 = a;
  }
  __syncthreads();
  const int p = blockIdx.x * 256 + tid;
  if (p >= npts) return;
  const float v = values[p];
  float a = sc0;
  #pragma unroll 8
  for (int j = 0; j < 64; ++j)
    a = fmaf(fmaxf(0.f, fmaf(v, sW1[j], sb1[j])), sWvO[j], a);
  VoOut[p] = a;
}

// ---------------- main attention kernel ----------------
// grid: B*64 blocks (one 64-m tile each), 1024 threads (16 waves).
// Round-6 post-mortem: spill fixed (88 VGPR), but with only 2 waves/SIMD the
// VALU and LDS pipes (each needing only ~110-125 us) sat idle ~60% of the
// time behind lgkm/vm waits. This round: 4 waves/SIMD via 1024-thread blocks
// (still 1 block/CU, grid=256). Inner loop byte-identical to round 6; per-wave
// n-iterations halve (8). Vo moves from LDS to direct global reads (L2-hot)
// to fit Ks 64KB + stats 64KB + Qs 16KB = 148 KB LDS.
__global__ void __launch_bounds__(1024)
attn_kernel(
    const float* __restrict__ Kt, const float* __restrict__ Qt,
    const float* __restrict__ Vo, const float* __restrict__ bo,
    float* __restrict__ out)
{
  __shared__ float Qs[64 * 64];      // [h][m_local]  16 KB
  __shared__ float Ks[16][4][256];   // [wave][buf][h8*32 + n32] 64 KB
  __shared__ float MtL[1024];        // [w][m_local]  final-merge staging 4 KB
  __shared__ float numL[8192];       // [w][j*64+lane] running numerator 32 KB
  __shared__ float denL[8192];       // [w][j*64+lane] running denominator 32 KB

  const int b    = blockIdx.x >> 6;
  const int m0   = (blockIdx.x & 63) << 6;
  const int tid  = threadIdx.x;
  const int w    = tid >> 6;         // 0..15
  const int lane = tid & 63;
  const int lm = lane >> 3, ln = lane & 7;

  const float* __restrict__ KtB = Kt + (size_t)b * 64 * NPTS;
  const float* __restrict__ QtB = Qt + (size_t)b * 64 * NPTS;
  const float* __restrict__ VoB = Vo + (size_t)b * NPTS;

  { // stage Q tile into LDS (coalesced float4); zero own stats
    const int h = tid >> 4, c16 = (tid & 15) * 4;
    *(float4*)&Qs[h * 64 + c16] = *(const float4*)&QtB[(size_t)h * NPTS + m0 + c16];
    #pragma unroll
    for (int j = 0; j < 8; ++j) {
      numL[w * 512 + j * 64 + lane] = 0.f;
      denL[w * 512 + j * 64 + lane] = 0.f;
    }
  }
  __syncthreads();   // drains vmcnt too -> clean counting below

  float acc[32];
  float Mt[8];
  #pragma unroll
  for (int x = 0; x < 32; ++x) acc[x] = 0.f;
  #pragma unroll
  for (int j = 0; j < 8; ++j) Mt[j] = __builtin_inff();

  const int hrow = lane >> 3;                 // 0..7: h row within a staging instr
  const int noff = w * 32 + (lane & 7) * 4;   // per-lane n column for staging

  // chunk c (0..63): h = (c&7)*8 + {0..7}, n base = (c>>3)*512 + w*32
  // one gload_lds16 instr = 64 lanes x 16 B = 1 KB = 8h x 32n
  #define ISSUE_K(c_) do { \
    const int I_ = (c_) >> 3, cc_ = (c_) & 7; \
    const float* s_ = KtB + (size_t)(cc_ * 8 + hrow) * NPTS + I_ * 512 + noff; \
    gload_lds16(s_, &Ks[w][(c_) & 3][0]); \
  } while (0)

  ISSUE_K(0);
  ISSUE_K(1);
  ISSUE_K(2);
  ISSUE_K(3);

  for (int I = 0; I < 8; ++I) {          // n-iterations (512 n each; wave owns 32)
    #pragma unroll
    for (int cc = 0; cc < 8; ++cc) {     // h-chunks (8 rows each)
      const int c = I * 8 + cc;
      // outstanding at this point: chunks c..min(c+3,63)
      if (I < 7 || cc < 5) asm volatile("s_waitcnt vmcnt(3)" ::: "memory");
      else if (cc == 5)    asm volatile("s_waitcnt vmcnt(2)" ::: "memory");
      else if (cc == 6)    asm volatile("s_waitcnt vmcnt(1)" ::: "memory");
      else                 asm volatile("s_waitcnt vmcnt(0)" ::: "memory");
      __builtin_amdgcn_sched_barrier(0);
      const float* __restrict__ Kw = &Ks[w][cc & 3][ln * 4];
      const float* __restrict__ Qh = &Qs[(cc * 8) * 64 + lm * 8];
      #pragma unroll 2
      for (int hh = 0; hh < 8; ++hh) {
        float q[8], k[4];
        *(float4*)&q[0] = *(const float4*)(Qh + hh * 64);
        *(float4*)&q[4] = *(const float4*)(Qh + hh * 64 + 4);
        *(float4*)&k[0] = *(const float4*)(Kw + hh * 32);
        #pragma unroll
        for (int j = 0; j < 8; ++j) {
          #pragma unroll
          for (int i = 0; i < 4; ++i)
            acc[j * 4 + i] += fabsf(k[i] - q[j]);   // v_sub + v_add |src|
        }
      }
      if (c + 4 < 64) ISSUE_K(c + 4);
    }

    { // epilogue for iteration I: online softmax update (min s -> min s^2)
      float vo[4];
      const int vb = I * 512 + w * 32 + ln * 4;
      *(float4*)&vo[0] = *(const float4*)&VoB[vb];   // global, L2-hot (16 KB/batch)
      #pragma unroll
      for (int j = 0; j < 8; ++j) {
        // acc >= 0, so min(s^2) == (min s)^2
        float rmin = fminf(fminf(acc[j*4+0], acc[j*4+1]), fminf(acc[j*4+2], acc[j*4+3]));
        rmin = fminf(rmin, __shfl_xor(rmin, 1));
        rmin = fminf(rmin, __shfl_xor(rmin, 2));
        rmin = fminf(rmin, __shfl_xor(rmin, 4));
        const float nM = fminf(Mt[j], rmin * rmin);
        const float sc = __builtin_amdgcn_exp2f(CC * (nM - Mt[j])); // inf start -> 0
        const int slot = w * 512 + j * 64 + lane;
        float nm = numL[slot] * sc;
        float dn = denL[slot] * sc;
        Mt[j] = nM;
        const float base = CC * nM;
        #pragma unroll
        for (int i = 0; i < 4; ++i) {
          const float a = acc[j * 4 + i];
          const float wgt = __builtin_amdgcn_exp2f(fmaf(-CC, a * a, base));
          dn += wgt;
          nm = fmaf(wgt, vo[i], nm);
          acc[j * 4 + i] = 0.f;
        }
        numL[slot] = nm;
        denL[slot] = dn;
      }
    }
  }

  // publish per-wave Mt (uniform across the 8 ln-lanes of each m)
  if (ln == 0) {
    #pragma unroll
    for (int j = 0; j < 8; ++j)
      MtL[w * 64 + lm * 8 + j] = Mt[j];
  }
  __syncthreads();

  if (tid < 64) {                  // merge the 16 waves' partial softmax states
    const int m = tid;             // m = lm*8 + j  ->  j = m&7, lm = m>>3
    float M = __builtin_inff();
    #pragma unroll
    for (int ww = 0; ww < 16; ++ww) M = fminf(M, MtL[ww * 64 + m]);
    float Ns = 0.f, Ds = 0.f;
    #pragma unroll
    for (int ww = 0; ww < 16; ++ww) {
      const float f = __builtin_amdgcn_exp2f(CC * (M - MtL[ww * 64 + m]));
      float ns = 0.f, ds = 0.f;
      #pragma unroll
      for (int l = 0; l < 8; ++l) {
        ns += numL[ww * 512 + (m & 7) * 64 + (m >> 3) * 8 + l];
        ds += denL[ww * 512 + (m & 7) * 64 + (m >> 3) * 8 + l];
      }
      Ns = fmaf(ns, f, Ns);
      Ds = fmaf(ds, f, Ds);
    }
    out[(size_t)b * NPTS + m0 + m] = Ns / Ds + bo[0];
  }
}

extern "C" void kernel_launch(void* const* d_in, const int* in_sizes, int n_in,
                              void* d_out, int out_size, void* d_ws, size_t ws_size,
                              hipStream_t stream)
{
  const float* coords_f = (const float*)d_in[0];
  const float* values_f = (const float*)d_in[1];
  const float* coords_t = (const float*)d_in[2];
  const float* Wk1 = (const float*)d_in[3];
  const float* bk1 = (const float*)d_in[4];
  const float* Wk2 = (const float*)d_in[5];
  const float* bk2 = (const float*)d_in[6];
  const float* Wq1 = (const float*)d_in[7];
  const float* bq1 = (const float*)d_in[8];
  const float* Wq2 = (const float*)d_in[9];
  const float* bq2 = (const float*)d_in[10];
  const float* Wv1 = (const float*)d_in[11];
  const float* bv1 = (const float*)d_in[12];
  const float* Wv2 = (const float*)d_in[13];
  const float* bv2 = (const float*)d_in[14];
  const float* Wo  = (const float*)d_in[15];
  const float* bo  = (const float*)d_in[16];

  const int B    = in_sizes[0] / (NPTS * 3);
  const int npts = B * NPTS;

  float* Kt  = (float*)d_ws;                       // [B][64][N]
  float* Qt  = Kt + (size_t)B * 64 * NPTS;         // [B][64][M]
  float* VoW = Qt + (size_t)B * 64 * NPTS;         // [B][N]

  feat_kernel<<<npts / 64, 256, 0, stream>>>(coords_f, Wk1, bk1, Wk2, bk2, Kt, npts);
  feat_kernel<<<npts / 64, 256, 0, stream>>>(coords_t, Wq1, bq1, Wq2, bq2, Qt, npts);
  vo_kernel<<<npts / 256, 256, 0, stream>>>(values_f, Wv1, bv1, Wv2, bv2, Wo, VoW, npts);
  attn_kernel<<<B * 64, 1024, 0, stream>>>(Kt, Qt, VoW, bo, (float*)d_out);
}

// Round 8
// 227.879 us; speedup vs baseline: 7.1590x; 1.3816x over previous
//
#include <hip/hip_runtime.h>
#include <math.h>

#define NPTS 4096
#define CC 0.7213475204444817f   // log2(e)/2 : exp(-s^2/2) = 2^(-CC*s^2)

__device__ __forceinline__ void gload_lds16(const float* g, float* l) {
  __builtin_amdgcn_global_load_lds(
      (const __attribute__((address_space(1))) void*)g,
      (__attribute__((address_space(3))) void*)l, 16, 0, 0);
}

// ---------------- feature MLP: coords[B,N,3] -> outT[b][h][n] (transposed) ----------------
__global__ __launch_bounds__(256) void feat_kernel(
    const float* __restrict__ coords, const float* __restrict__ W1,
    const float* __restrict__ b1, const float* __restrict__ W2,
    const float* __restrict__ b2, float* __restrict__ outT, int npts)
{
  __shared__ float sW1[3 * 64], sb1[64], sW2[64 * 64], sb2[64];
  const int tid = threadIdx.x;
  for (int i = tid; i < 192; i += 256) sW1[i] = W1[i];
  if (tid < 64) { sb1[tid] = b1[tid]; sb2[tid] = b2[tid]; }
  for (int i = tid; i < 4096; i += 256) sW2[i] = W2[i];
  __syncthreads();

  const int p  = blockIdx.x * 64 + (tid & 63);   // point index (consecutive threads -> consecutive n)
  const int qh = (tid >> 6) * 16;                // h-quarter handled by this thread
  if (p >= npts) return;
  const float c0 = coords[p * 3 + 0], c1 = coords[p * 3 + 1], c2 = coords[p * 3 + 2];

  float hid[64];
  #pragma unroll
  for (int j = 0; j < 64; ++j)
    hid[j] = fmaxf(0.f, fmaf(c0, sW1[j], fmaf(c1, sW1[64 + j], fmaf(c2, sW1[128 + j], sb1[j]))));

  float acc[16];
  #pragma unroll
  for (int h = 0; h < 16; ++h) acc[h] = sb2[qh + h];
  for (int j = 0; j < 64; ++j) {
    const float hj = hid[j];
    const float4* wrow = (const float4*)&sW2[j * 64 + qh];
    #pragma unroll
    for (int hq = 0; hq < 4; ++hq) {
      float4 wv = wrow[hq];
      acc[hq * 4 + 0] = fmaf(hj, wv.x, acc[hq * 4 + 0]);
      acc[hq * 4 + 1] = fmaf(hj, wv.y, acc[hq * 4 + 1]);
      acc[hq * 4 + 2] = fmaf(hj, wv.z, acc[hq * 4 + 2]);
      acc[hq * 4 + 3] = fmaf(hj, wv.w, acc[hq * 4 + 3]);
    }
  }
  const int b = p / NPTS, n = p % NPTS;
  #pragma unroll
  for (int h = 0; h < 16; ++h)
    outT[(size_t)(b * 64 + qh + h) * NPTS + n] = acc[h];
}

// ---------------- Vo kernel: Vo[b,n] = MLP_v(values)[b,n,:] . Wo ----------------
__global__ __launch_bounds__(256) void vo_kernel(
    const float* __restrict__ values, const float* __restrict__ Wv1,
    const float* __restrict__ bv1, const float* __restrict__ Wv2,
    const float* __restrict__ bv2, const float* __restrict__ Wo,
    float* __restrict__ VoOut, int npts)
{
  __shared__ float sWvO[64], sW1[64], sb1[64], sc0;
  const int tid = threadIdx.x;
  if (tid < 64) {
    float a = 0.f;
    for (int h = 0; h < 64; ++h) a = fmaf(Wv2[tid * 64 + h], Wo[h], a);
    sWvO[tid] = a;
    sW1[tid] = Wv1[tid];
    sb1[tid] = bv1[tid];
  } else if (tid == 64) {
    float a = 0.f;
    for (int h = 0; h < 64; ++h) a = fmaf(bv2[h], Wo[h], a);
    sc0 = a;
  }
  __syncthreads();
  const int p = blockIdx.x * 256 + tid;
  if (p >= npts) return;
  const float v = values[p];
  float a = sc0;
  #pragma unroll 8
  for (int j = 0; j < 64; ++j)
    a = fmaf(fmaxf(0.f, fmaf(v, sW1[j], sb1[j])), sWvO[j], a);
  VoOut[p] = a;
}

// ---------------- main attention kernel ----------------
// grid: B*64 blocks (one 64-m tile each), 1024 threads (16 waves).
// Round-7 post-mortem: VALU busy-time constant across occupancy (~280 us) at
// ~5.3 issued VALU per element-pair vs ideal 2 — codegen bloat (VGPR_Count=52
// says acc lived in AGPRs, paying moves per update, plus unfused abs). Fix:
// inline-asm core pinning exactly v_sub_f32 + v_add_f32 |d| per pair with
// "v"-class constraints (forces arch-VGPR accumulators). Structure otherwise
// identical to round 7.
__global__ void __launch_bounds__(1024)
attn_kernel(
    const float* __restrict__ Kt, const float* __restrict__ Qt,
    const float* __restrict__ Vo, const float* __restrict__ bo,
    float* __restrict__ out)
{
  __shared__ float Qs[64 * 64];      // [h][m_local]  16 KB
  __shared__ float Ks[16][4][256];   // [wave][buf][h8*32 + n32] 64 KB
  __shared__ float MtL[1024];        // [w][m_local]  final-merge staging 4 KB
  __shared__ float numL[8192];       // [w][j*64+lane] running numerator 32 KB
  __shared__ float denL[8192];       // [w][j*64+lane] running denominator 32 KB

  const int b    = blockIdx.x >> 6;
  const int m0   = (blockIdx.x & 63) << 6;
  const int tid  = threadIdx.x;
  const int w    = tid >> 6;         // 0..15
  const int lane = tid & 63;
  const int lm = lane >> 3, ln = lane & 7;

  const float* __restrict__ KtB = Kt + (size_t)b * 64 * NPTS;
  const float* __restrict__ QtB = Qt + (size_t)b * 64 * NPTS;
  const float* __restrict__ VoB = Vo + (size_t)b * NPTS;

  { // stage Q tile into LDS (coalesced float4); zero own stats
    const int h = tid >> 4, c16 = (tid & 15) * 4;
    *(float4*)&Qs[h * 64 + c16] = *(const float4*)&QtB[(size_t)h * NPTS + m0 + c16];
    #pragma unroll
    for (int j = 0; j < 8; ++j) {
      numL[w * 512 + j * 64 + lane] = 0.f;
      denL[w * 512 + j * 64 + lane] = 0.f;
    }
  }
  __syncthreads();   // drains vmcnt too -> clean counting below

  float acc[32];
  float Mt[8];
  #pragma unroll
  for (int x = 0; x < 32; ++x) acc[x] = 0.f;
  #pragma unroll
  for (int j = 0; j < 8; ++j) Mt[j] = __builtin_inff();

  const int hrow = lane >> 3;                 // 0..7: h row within a staging instr
  const int noff = w * 32 + (lane & 7) * 4;   // per-lane n column for staging

  // chunk c (0..63): h = (c&7)*8 + {0..7}, n base = (c>>3)*512 + w*32
  // one gload_lds16 instr = 64 lanes x 16 B = 1 KB = 8h x 32n
  #define ISSUE_K(c_) do { \
    const int I_ = (c_) >> 3, cc_ = (c_) & 7; \
    const float* s_ = KtB + (size_t)(cc_ * 8 + hrow) * NPTS + I_ * 512 + noff; \
    gload_lds16(s_, &Ks[w][(c_) & 3][0]); \
  } while (0)

  ISSUE_K(0);
  ISSUE_K(1);
  ISSUE_K(2);
  ISSUE_K(3);

  for (int I = 0; I < 8; ++I) {          // n-iterations (512 n each; wave owns 32)
    #pragma unroll
    for (int cc = 0; cc < 8; ++cc) {     // h-chunks (8 rows each)
      const int c = I * 8 + cc;
      // outstanding at this point: chunks c..min(c+3,63)
      if (I < 7 || cc < 5) asm volatile("s_waitcnt vmcnt(3)" ::: "memory");
      else if (cc == 5)    asm volatile("s_waitcnt vmcnt(2)" ::: "memory");
      else if (cc == 6)    asm volatile("s_waitcnt vmcnt(1)" ::: "memory");
      else                 asm volatile("s_waitcnt vmcnt(0)" ::: "memory");
      __builtin_amdgcn_sched_barrier(0);
      const float* __restrict__ Kw = &Ks[w][cc & 3][ln * 4];
      const float* __restrict__ Qh = &Qs[(cc * 8) * 64 + lm * 8];
      #pragma unroll 2
      for (int hh = 0; hh < 8; ++hh) {
        float q[8], k[4];
        *(float4*)&q[0] = *(const float4*)(Qh + hh * 64);
        *(float4*)&q[4] = *(const float4*)(Qh + hh * 64 + 4);
        *(float4*)&k[0] = *(const float4*)(Kw + hh * 32);
        #pragma unroll
        for (int j = 0; j < 8; ++j) {
          #pragma unroll
          for (int i = 0; i < 4; ++i) {
            float d;
            // exactly 2 VALU per pair; "v" pins acc to arch VGPRs
            asm("v_sub_f32 %0, %2, %3\n\t"
                "v_add_f32 %1, %1, |%0|"
                : "=&v"(d), "+v"(acc[j * 4 + i])
                : "v"(k[i]), "v"(q[j]));
          }
        }
      }
      if (c + 4 < 64) ISSUE_K(c + 4);
    }

    { // epilogue for iteration I: online softmax update (min s -> min s^2)
      float vo[4];
      const int vb = I * 512 + w * 32 + ln * 4;
      *(float4*)&vo[0] = *(const float4*)&VoB[vb];   // global, L2-hot (16 KB/batch)
      #pragma unroll
      for (int j = 0; j < 8; ++j) {
        // acc >= 0, so min(s^2) == (min s)^2
        float rmin = fminf(fminf(acc[j*4+0], acc[j*4+1]), fminf(acc[j*4+2], acc[j*4+3]));
        rmin = fminf(rmin, __shfl_xor(rmin, 1));
        rmin = fminf(rmin, __shfl_xor(rmin, 2));
        rmin = fminf(rmin, __shfl_xor(rmin, 4));
        const float nM = fminf(Mt[j], rmin * rmin);
        const float sc = __builtin_amdgcn_exp2f(CC * (nM - Mt[j])); // inf start -> 0
        const int slot = w * 512 + j * 64 + lane;
        float nm = numL[slot] * sc;
        float dn = denL[slot] * sc;
        Mt[j] = nM;
        const float base = CC * nM;
        #pragma unroll
        for (int i = 0; i < 4; ++i) {
          const float a = acc[j * 4 + i];
          const float wgt = __builtin_amdgcn_exp2f(fmaf(-CC, a * a, base));
          dn += wgt;
          nm = fmaf(wgt, vo[i], nm);
          acc[j * 4 + i] = 0.f;
        }
        numL[slot] = nm;
        denL[slot] = dn;
      }
    }
  }

  // publish per-wave Mt (uniform across the 8 ln-lanes of each m)
  if (ln == 0) {
    #pragma unroll
    for (int j = 0; j < 8; ++j)
      MtL[w * 64 + lm * 8 + j] = Mt[j];
  }
  __syncthreads();

  if (tid < 64) {                  // merge the 16 waves' partial softmax states
    const int m = tid;             // m = lm*8 + j  ->  j = m&7, lm = m>>3
    float M = __builtin_inff();
    #pragma unroll
    for (int ww = 0; ww < 16; ++ww) M = fminf(M, MtL[ww * 64 + m]);
    float Ns = 0.f, Ds = 0.f;
    #pragma unroll
    for (int ww = 0; ww < 16; ++ww) {
      const float f = __builtin_amdgcn_exp2f(CC * (M - MtL[ww * 64 + m]));
      float ns = 0.f, ds = 0.f;
      #pragma unroll
      for (int l = 0; l < 8; ++l) {
        ns += numL[ww * 512 + (m & 7) * 64 + (m >> 3) * 8 + l];
        ds += denL[ww * 512 + (m & 7) * 64 + (m >> 3) * 8 + l];
      }
      Ns = fmaf(ns, f, Ns);
      Ds = fmaf(ds, f, Ds);
    }
    out[(size_t)b * NPTS + m0 + m] = Ns / Ds + bo[0];
  }
}

extern "C" void kernel_launch(void* const* d_in, const int* in_sizes, int n_in,
                              void* d_out, int out_size, void* d_ws, size_t ws_size,
                              hipStream_t stream)
{
  const float* coords_f = (const float*)d_in[0];
  const float* values_f = (const float*)d_in[1];
  const float* coords_t = (const float*)d_in[2];
  const float* Wk1 = (const float*)d_in[3];
  const float* bk1 = (const float*)d_in[4];
  const float* Wk2 = (const float*)d_in[5];
  const float* bk2 = (const float*)d_in[6];
  const float* Wq1 = (const float*)d_in[7];
  const float* bq1 = (const float*)d_in[8];
  const float* Wq2 = (const float*)d_in[9];
  const float* bq2 = (const float*)d_in[10];
  const float* Wv1 = (const float*)d_in[11];
  const float* bv1 = (const float*)d_in[12];
  const float* Wv2 = (const float*)d_in[13];
  const float* bv2 = (const float*)d_in[14];
  const float* Wo  = (const float*)d_in[15];
  const float* bo  = (const float*)d_in[16];

  const int B    = in_sizes[0] / (NPTS * 3);
  const int npts = B * NPTS;

  float* Kt  = (float*)d_ws;                       // [B][64][N]
  float* Qt  = Kt + (size_t)B * 64 * NPTS;         // [B][64][M]
  float* VoW = Qt + (size_t)B * 64 * NPTS;         // [B][N]

  feat_kernel<<<npts / 64, 256, 0, stream>>>(coords_f, Wk1, bk1, Wk2, bk2, Kt, npts);
  feat_kernel<<<npts / 64, 256, 0, stream>>>(coords_t, Wq1, bq1, Wq2, bq2, Qt, npts);
  vo_kernel<<<npts / 256, 256, 0, stream>>>(values_f, Wv1, bv1, Wv2, bv2, Wo, VoW, npts);
  attn_kernel<<<B * 64, 1024, 0, stream>>>(Kt, Qt, VoW, bo, (float*)d_out);
}

// Round 9
// 217.886 us; speedup vs baseline: 7.4874x; 1.0459x over previous
//
#include <hip/hip_runtime.h>
#include <math.h>

#define NPTS 4096
#define CC 0.7213475204444817f   // log2(e)/2 : exp(-s^2/2) = 2^(-CC*s^2)

__device__ __forceinline__ void gload_lds16(const float* g, float* l) {
  __builtin_amdgcn_global_load_lds(
      (const __attribute__((address_space(1))) void*)g,
      (__attribute__((address_space(3))) void*)l, 16, 0, 0);
}

// ---------------- feature MLP: coords[B,N,3] -> outT[b][h][n] (transposed) ----------------
__global__ __launch_bounds__(256) void feat_kernel(
    const float* __restrict__ coords, const float* __restrict__ W1,
    const float* __restrict__ b1, const float* __restrict__ W2,
    const float* __restrict__ b2, float* __restrict__ outT, int npts)
{
  __shared__ float sW1[3 * 64], sb1[64], sW2[64 * 64], sb2[64];
  const int tid = threadIdx.x;
  for (int i = tid; i < 192; i += 256) sW1[i] = W1[i];
  if (tid < 64) { sb1[tid] = b1[tid]; sb2[tid] = b2[tid]; }
  for (int i = tid; i < 4096; i += 256) sW2[i] = W2[i];
  __syncthreads();

  const int p  = blockIdx.x * 64 + (tid & 63);   // point index (consecutive threads -> consecutive n)
  const int qh = (tid >> 6) * 16;                // h-quarter handled by this thread
  if (p >= npts) return;
  const float c0 = coords[p * 3 + 0], c1 = coords[p * 3 + 1], c2 = coords[p * 3 + 2];

  float hid[64];
  #pragma unroll
  for (int j = 0; j < 64; ++j)
    hid[j] = fmaxf(0.f, fmaf(c0, sW1[j], fmaf(c1, sW1[64 + j], fmaf(c2, sW1[128 + j], sb1[j]))));

  float acc[16];
  #pragma unroll
  for (int h = 0; h < 16; ++h) acc[h] = sb2[qh + h];
  for (int j = 0; j < 64; ++j) {
    const float hj = hid[j];
    const float4* wrow = (const float4*)&sW2[j * 64 + qh];
    #pragma unroll
    for (int hq = 0; hq < 4; ++hq) {
      float4 wv = wrow[hq];
      acc[hq * 4 + 0] = fmaf(hj, wv.x, acc[hq * 4 + 0]);
      acc[hq * 4 + 1] = fmaf(hj, wv.y, acc[hq * 4 + 1]);
      acc[hq * 4 + 2] = fmaf(hj, wv.z, acc[hq * 4 + 2]);
      acc[hq * 4 + 3] = fmaf(hj, wv.w, acc[hq * 4 + 3]);
    }
  }
  const int b = p / NPTS, n = p % NPTS;
  #pragma unroll
  for (int h = 0; h < 16; ++h)
    outT[(size_t)(b * 64 + qh + h) * NPTS + n] = acc[h];
}

// ---------------- Vo kernel: Vo[b,n] = MLP_v(values)[b,n,:] . Wo ----------------
__global__ __launch_bounds__(256) void vo_kernel(
    const float* __restrict__ values, const float* __restrict__ Wv1,
    const float* __restrict__ bv1, const float* __restrict__ Wv2,
    const float* __restrict__ bv2, const float* __restrict__ Wo,
    float* __restrict__ VoOut, int npts)
{
  __shared__ float sWvO[64], sW1[64], sb1[64], sc0;
  const int tid = threadIdx.x;
  if (tid < 64) {
    float a = 0.f;
    for (int h = 0; h < 64; ++h) a = fmaf(Wv2[tid * 64 + h], Wo[h], a);
    sWvO[tid] = a;
    sW1[tid] = Wv1[tid];
    sb1[tid] = bv1[tid];
  } else if (tid == 64) {
    float a = 0.f;
    for (int h = 0; h < 64; ++h) a = fmaf(bv2[h], Wo[h], a);
    sc0 = a;
  }
  __syncthreads();
  const int p = blockIdx.x * 256 + tid;
  if (p >= npts) return;
  const float v = values[p];
  float a = sc0;
  #pragma unroll 8
  for (int j = 0; j < 64; ++j)
    a = fmaf(fmaxf(0.f, fmaf(v, sW1[j], sb1[j])), sWvO[j], a);
  VoOut[p] = a;
}

// ---------------- main attention kernel ----------------
// grid: B*64 blocks (one 64-m tile each), 1024 threads (16 waves).
// Round-8 post-mortem: dur 221 us = SUM of VALU (~113 us) and LDS-pipe
// (~123 us) times -> the pipes serialize on lgkm waits (too little VALU work
// per load burst). Fix: 8m x 8n lane tile (acc[64], asm-pinned): 4 b128 feed
// 128 VALU (32:1 vs 21:1), total b128 reads drop 1.5x -> LDS ~90 us < VALU
// ~113 us, VALU becomes the single binding pipe. Wave covers 64m x 64n;
// 4 outer iterations of 1024 n.
__global__ void __launch_bounds__(1024)
attn_kernel(
    const float* __restrict__ Kt, const float* __restrict__ Qt,
    const float* __restrict__ Vo, const float* __restrict__ bo,
    float* __restrict__ out)
{
  __shared__ float Qs[64 * 64];      // [h][m_local]  16 KB
  __shared__ float Ks[16][2][512];   // [wave][buf][h8][64n] 64 KB
  __shared__ float MtL[1024];        // [w][m_local]  final-merge staging 4 KB
  __shared__ float numL[8192];       // [w][j*64+lane] running numerator 32 KB
  __shared__ float denL[8192];       // [w][j*64+lane] running denominator 32 KB

  const int b    = blockIdx.x >> 6;
  const int m0   = (blockIdx.x & 63) << 6;
  const int tid  = threadIdx.x;
  const int w    = tid >> 6;         // 0..15
  const int lane = tid & 63;
  const int lm = lane >> 3, ln = lane & 7;

  const float* __restrict__ KtB = Kt + (size_t)b * 64 * NPTS;
  const float* __restrict__ QtB = Qt + (size_t)b * 64 * NPTS;
  const float* __restrict__ VoB = Vo + (size_t)b * NPTS;

  { // stage Q tile into LDS (coalesced float4); zero own stats
    const int h = tid >> 4, c16 = (tid & 15) * 4;
    *(float4*)&Qs[h * 64 + c16] = *(const float4*)&QtB[(size_t)h * NPTS + m0 + c16];
    #pragma unroll
    for (int j = 0; j < 8; ++j) {
      numL[w * 512 + j * 64 + lane] = 0.f;
      denL[w * 512 + j * 64 + lane] = 0.f;
    }
  }
  __syncthreads();   // drains vmcnt too -> clean counting below

  float acc[64];
  float Mt[8];
  #pragma unroll
  for (int x = 0; x < 64; ++x) acc[x] = 0.f;
  #pragma unroll
  for (int j = 0; j < 8; ++j) Mt[j] = __builtin_inff();

  const int hrow = lane >> 4;                 // 0..3: h row within a staging instr
  const int noff = w * 64 + (lane & 15) * 4;  // per-lane n column for staging

  // chunk c (0..31): h = (c&7)*8 + {0..7}, n base = (c>>3)*1024 + w*64
  // two gload_lds16 instrs of 1 KB each (4 h-rows x 64 n per instr)
  #define ISSUE_K(c_) do { \
    const int I_ = (c_) >> 3, cc_ = (c_) & 7; \
    const float* s_ = KtB + (size_t)(cc_ * 8 + hrow) * NPTS + I_ * 1024 + noff; \
    float* d_ = &Ks[w][(c_) & 1][0]; \
    gload_lds16(s_, d_); \
    gload_lds16(s_ + 4 * NPTS, d_ + 256); \
  } while (0)

  ISSUE_K(0);
  ISSUE_K(1);

  for (int I = 0; I < 4; ++I) {          // n-iterations (1024 n each; wave owns 64)
    #pragma unroll
    for (int cc = 0; cc < 8; ++cc) {     // h-chunks (8 rows each)
      const int c = I * 8 + cc;
      if (c < 31) asm volatile("s_waitcnt vmcnt(2)" ::: "memory");
      else        asm volatile("s_waitcnt vmcnt(0)" ::: "memory");
      __builtin_amdgcn_sched_barrier(0);
      const float* __restrict__ Kw = &Ks[w][c & 1][ln * 8];
      const float* __restrict__ Qh = &Qs[(cc * 8) * 64 + lm * 8];
      #pragma unroll 2
      for (int hh = 0; hh < 8; ++hh) {
        float q[8], k[8];
        *(float4*)&q[0] = *(const float4*)(Qh + hh * 64);
        *(float4*)&q[4] = *(const float4*)(Qh + hh * 64 + 4);
        *(float4*)&k[0] = *(const float4*)(Kw + hh * 64);
        *(float4*)&k[4] = *(const float4*)(Kw + hh * 64 + 4);
        #pragma unroll
        for (int j = 0; j < 8; ++j) {
          #pragma unroll
          for (int i = 0; i < 8; ++i) {
            float d;
            // exactly 2 VALU per pair; "v" pins acc to arch VGPRs
            asm("v_sub_f32 %0, %2, %3\n\t"
                "v_add_f32 %1, %1, |%0|"
                : "=&v"(d), "+v"(acc[j * 8 + i])
                : "v"(k[i]), "v"(q[j]));
          }
        }
      }
      if (c + 2 < 32) ISSUE_K(c + 2);
    }

    { // epilogue for iteration I: online softmax update (min s -> min s^2)
      float vo[8];
      const int vb = I * 1024 + w * 64 + ln * 8;
      *(float4*)&vo[0] = *(const float4*)&VoB[vb];       // global, L2-hot
      *(float4*)&vo[4] = *(const float4*)&VoB[vb + 4];
      #pragma unroll
      for (int j = 0; j < 8; ++j) {
        // acc >= 0, so min(s^2) == (min s)^2
        float rmin = fminf(fminf(fminf(acc[j*8+0], acc[j*8+1]), fminf(acc[j*8+2], acc[j*8+3])),
                           fminf(fminf(acc[j*8+4], acc[j*8+5]), fminf(acc[j*8+6], acc[j*8+7])));
        rmin = fminf(rmin, __shfl_xor(rmin, 1));
        rmin = fminf(rmin, __shfl_xor(rmin, 2));
        rmin = fminf(rmin, __shfl_xor(rmin, 4));
        const float nM = fminf(Mt[j], rmin * rmin);
        const float sc = __builtin_amdgcn_exp2f(CC * (nM - Mt[j])); // inf start -> 0
        const int slot = w * 512 + j * 64 + lane;
        float nm = numL[slot] * sc;
        float dn = denL[slot] * sc;
        Mt[j] = nM;
        const float base = CC * nM;
        #pragma unroll
        for (int i = 0; i < 8; ++i) {
          const float a = acc[j * 8 + i];
          const float wgt = __builtin_amdgcn_exp2f(fmaf(-CC, a * a, base));
          dn += wgt;
          nm = fmaf(wgt, vo[i], nm);
          acc[j * 8 + i] = 0.f;
        }
        numL[slot] = nm;
        denL[slot] = dn;
      }
    }
  }

  // publish per-wave Mt (uniform across the 8 ln-lanes of each m)
  if (ln == 0) {
    #pragma unroll
    for (int j = 0; j < 8; ++j)
      MtL[w * 64 + lm * 8 + j] = Mt[j];
  }
  __syncthreads();

  if (tid < 64) {                  // merge the 16 waves' partial softmax states
    const int m = tid;             // m = lm*8 + j  ->  j = m&7, lm = m>>3
    float M = __builtin_inff();
    #pragma unroll
    for (int ww = 0; ww < 16; ++ww) M = fminf(M, MtL[ww * 64 + m]);
    float Ns = 0.f, Ds = 0.f;
    #pragma unroll
    for (int ww = 0; ww < 16; ++ww) {
      const float f = __builtin_amdgcn_exp2f(CC * (M - MtL[ww * 64 + m]));
      float ns = 0.f, ds = 0.f;
      #pragma unroll
      for (int l = 0; l < 8; ++l) {
        ns += numL[ww * 512 + (m & 7) * 64 + (m >> 3) * 8 + l];
        ds += denL[ww * 512 + (m & 7) * 64 + (m >> 3) * 8 + l];
      }
      Ns = fmaf(ns, f, Ns);
      Ds = fmaf(ds, f, Ds);
    }
    out[(size_t)b * NPTS + m0 + m] = Ns / Ds + bo[0];
  }
}

extern "C" void kernel_launch(void* const* d_in, const int* in_sizes, int n_in,
                              void* d_out, int out_size, void* d_ws, size_t ws_size,
                              hipStream_t stream)
{
  const float* coords_f = (const float*)d_in[0];
  const float* values_f = (const float*)d_in[1];
  const float* coords_t = (const float*)d_in[2];
  const float* Wk1 = (const float*)d_in[3];
  const float* bk1 = (const float*)d_in[4];
  const float* Wk2 = (const float*)d_in[5];
  const float* bk2 = (const float*)d_in[6];
  const float* Wq1 = (const float*)d_in[7];
  const float* bq1 = (const float*)d_in[8];
  const float* Wq2 = (const float*)d_in[9];
  const float* bq2 = (const float*)d_in[10];
  const float* Wv1 = (const float*)d_in[11];
  const float* bv1 = (const float*)d_in[12];
  const float* Wv2 = (const float*)d_in[13];
  const float* bv2 = (const float*)d_in[14];
  const float* Wo  = (const float*)d_in[15];
  const float* bo  = (const float*)d_in[16];

  const int B    = in_sizes[0] / (NPTS * 3);
  const int npts = B * NPTS;

  float* Kt  = (float*)d_ws;                       // [B][64][N]
  float* Qt  = Kt + (size_t)B * 64 * NPTS;         // [B][64][M]
  float* VoW = Qt + (size_t)B * 64 * NPTS;         // [B][N]

  feat_kernel<<<npts / 64, 256, 0, stream>>>(coords_f, Wk1, bk1, Wk2, bk2, Kt, npts);
  feat_kernel<<<npts / 64, 256, 0, stream>>>(coords_t, Wq1, bq1, Wq2, bq2, Qt, npts);
  vo_kernel<<<npts / 256, 256, 0, stream>>>(values_f, Wv1, bv1, Wv2, bv2, Wo, VoW, npts);
  attn_kernel<<<B * 64, 1024, 0, stream>>>(Kt, Qt, VoW, bo, (float*)d_out);
}